// Round 1
// baseline (351.594 us; speedup 1.0000x reference)
//
#include <hip/hip_runtime.h>

#define D256 256
#define TOTROWS 65536   // B*A*I = 4*32*512
#define BM 128
#define NBLK (TOTROWS / BM)   // 512
#define NT 512                // 8 waves

typedef unsigned short u16;
typedef unsigned int u32;
typedef __attribute__((ext_vector_type(8))) short bf16x8;
typedef __attribute__((ext_vector_type(16))) float f32x16;

__device__ __forceinline__ float b2f(u16 u) {
  union { u32 i; float f; } v; v.i = ((u32)u) << 16; return v.f;
}
__device__ __forceinline__ u16 f2b(float f) {
  union { float f; u32 i; } v; v.f = f;
  return (u16)((v.i + 0x7fffu + ((v.i >> 16) & 1u)) >> 16);  // RNE
}
__device__ __forceinline__ u32 scale2(u32 u, float s) {
  float lo = b2f((u16)(u & 0xffffu)) * s;
  float hi = b2f((u16)(u >> 16)) * s;
  return (u32)f2b(lo) | ((u32)f2b(hi) << 16);
}

// attn1 -> Wb[0] (as-is, row-major [j][k]), attn2 -> Wb[1]
__global__ void copy_convert(const float* __restrict__ a1,
                             const float* __restrict__ a2,
                             u16* __restrict__ out) {
  const int m = blockIdx.y;
  const float* src = m ? a2 : a1;
  const int idx = blockIdx.x * 256 + threadIdx.x;
  out[m * 65536 + idx] = f2b(src[idx]);
}

// W1 -> Wb[2] transposed ([n][j] = W1[j][n]), W2 -> Wb[3]
__global__ void transpose_convert(const float* __restrict__ W1,
                                  const float* __restrict__ W2,
                                  u16* __restrict__ out) {
  __shared__ float tile[32][33];
  const int m = blockIdx.z;
  const float* src = m ? W2 : W1;
  const int bx = blockIdx.x, by = blockIdx.y;
  const int tx = threadIdx.x, ty = threadIdx.y;
#pragma unroll
  for (int i = ty; i < 32; i += 8)
    tile[i][tx] = src[(by * 32 + i) * 256 + bx * 32 + tx];
  __syncthreads();
#pragma unroll
  for (int i = ty; i < 32; i += 8)
    out[m * 65536 + (bx * 32 + i) * 256 + by * 32 + tx] = f2b(tile[tx][i]);
}

__global__ __launch_bounds__(NT, 2)
void fused(const float* __restrict__ X0g, const float* __restrict__ X1g,
           const u16* __restrict__ Wb, float* __restrict__ outg) {
  __shared__ u16 lX0[BM][D256];   // 64 KB
  __shared__ u16 lX1[BM][D256];   // 64 KB
  __shared__ float sp0[BM], sp1[BM], sc0[BM], sc1[BM];

  const int t = threadIdx.x;
  const int row0 = blockIdx.x * BM;

  if (t < BM) { sp0[t] = 0.f; sp1[t] = 0.f; }

  // ---- stage X tiles: fp32 global -> bf16 LDS (read inputs exactly once) ----
  {
    const float4* g0 = (const float4*)(X0g + (size_t)row0 * D256);
    const float4* g1 = (const float4*)(X1g + (size_t)row0 * D256);
    ushort4* s0 = (ushort4*)&lX0[0][0];
    ushort4* s1 = (ushort4*)&lX1[0][0];
#pragma unroll
    for (int i = 0; i < 16; i++) {
      const int e = i * NT + t;   // 8192 float4 per tile
      float4 a = g0[e];
      float4 b = g1[e];
      ushort4 pa, pb;
      pa.x = f2b(a.x); pa.y = f2b(a.y); pa.z = f2b(a.z); pa.w = f2b(a.w);
      pb.x = f2b(b.x); pb.y = f2b(b.y); pb.z = f2b(b.z); pb.w = f2b(b.w);
      s0[e] = pa;
      s1[e] = pb;
    }
  }
  __syncthreads();

  const int ln  = t & 63;
  const int wv  = t >> 6;    // wave 0..7, owns 32-col strip
  const int l31 = ln & 31;
  const int lh  = ln >> 5;
  const int cb  = wv * 32;

  // ---- gating: s0[r] = sum_j X1[r,j] * (X0 @ attn1^T)[r,j]; s1 symmetric ----
#pragma unroll
  for (int g = 0; g < 2; g++) {
    const u16* Wg = Wb + (g ? 65536 : 0);
    const u16(*Am)[D256] = g ? lX1 : lX0;
    const u16(*Om)[D256] = g ? lX0 : lX1;
    float* sp = g ? sp1 : sp0;

    f32x16 acc[4];
#pragma unroll
    for (int ms = 0; ms < 4; ms++)
#pragma unroll
      for (int i = 0; i < 16; i++) acc[ms][i] = 0.f;

    const u16* wrow = Wg + (cb + l31) * 256 + lh * 8;
#pragma unroll 4
    for (int k = 0; k < 16; k++) {            // K=256, 16 per MFMA
      bf16x8 bf = *(const bf16x8*)(wrow + k * 16);
#pragma unroll
      for (int ms = 0; ms < 4; ms++) {
        bf16x8 af = *(const bf16x8*)(&Am[ms * 32 + l31][k * 16 + lh * 8]);
        acc[ms] = __builtin_amdgcn_mfma_f32_32x32x16_bf16(af, bf, acc[ms], 0, 0, 0);
      }
    }

    // multiply by other operand, reduce over the 32 cols of this strip
#pragma unroll
    for (int ms = 0; ms < 4; ms++) {
#pragma unroll
      for (int r = 0; r < 16; r++) {
        const int row = ms * 32 + (r & 3) + 8 * (r >> 2) + 4 * lh;
        float v = acc[ms][r] * b2f(Om[row][cb + l31]);
        v += __shfl_xor(v, 1, 32);
        v += __shfl_xor(v, 2, 32);
        v += __shfl_xor(v, 4, 32);
        v += __shfl_xor(v, 8, 32);
        v += __shfl_xor(v, 16, 32);
        if (l31 == 0) atomicAdd(&sp[row], v);
      }
    }
  }
  __syncthreads();

  if (t < BM) {
    sc0[t] = 1.f + 1.f / (1.f + __expf(-sp0[t]));
    sc1[t] = 1.f + 1.f / (1.f + __expf(-sp1[t]));
  }
  __syncthreads();

  // ---- rescale rows in place: (1+g) * x, bf16 ----
  {
    uint2* p0 = (uint2*)&lX0[0][0];
    uint2* p1 = (uint2*)&lX1[0][0];
#pragma unroll
    for (int i = 0; i < 16; i++) {
      const int c = i * NT + t;     // 8192 uint2 chunks per tile; 64 per row
      const int row = c >> 6;       // wave-uniform -> broadcast scale read
      const float s0v = sc0[row];
      const float s1v = sc1[row];
      uint2 a = p0[c];
      a.x = scale2(a.x, s0v); a.y = scale2(a.y, s0v);
      p0[c] = a;
      uint2 b = p1[c];
      b.x = scale2(b.x, s1v); b.y = scale2(b.y, s1v);
      p1[c] = b;
    }
  }
  __syncthreads();

  // ---- projection: out = r0 @ W1 + r1 @ W2 (concatenated K=512) ----
  {
    f32x16 acc[4];
#pragma unroll
    for (int ms = 0; ms < 4; ms++)
#pragma unroll
      for (int i = 0; i < 16; i++) acc[ms][i] = 0.f;

    const u16* w1r = Wb + 2 * 65536 + (cb + l31) * 256 + lh * 8;
    const u16* w2r = Wb + 3 * 65536 + (cb + l31) * 256 + lh * 8;
#pragma unroll 4
    for (int k = 0; k < 16; k++) {
      bf16x8 bf = *(const bf16x8*)(w1r + k * 16);
#pragma unroll
      for (int ms = 0; ms < 4; ms++) {
        bf16x8 af = *(const bf16x8*)(&lX0[ms * 32 + l31][k * 16 + lh * 8]);
        acc[ms] = __builtin_amdgcn_mfma_f32_32x32x16_bf16(af, bf, acc[ms], 0, 0, 0);
      }
    }
#pragma unroll 4
    for (int k = 0; k < 16; k++) {
      bf16x8 bf = *(const bf16x8*)(w2r + k * 16);
#pragma unroll
      for (int ms = 0; ms < 4; ms++) {
        bf16x8 af = *(const bf16x8*)(&lX1[ms * 32 + l31][k * 16 + lh * 8]);
        acc[ms] = __builtin_amdgcn_mfma_f32_32x32x16_bf16(af, bf, acc[ms], 0, 0, 0);
      }
    }

    float* op = outg + (size_t)row0 * 256 + cb + l31;
#pragma unroll
    for (int ms = 0; ms < 4; ms++) {
#pragma unroll
      for (int r = 0; r < 16; r++) {
        const int row = ms * 32 + (r & 3) + 8 * (r >> 2) + 4 * lh;
        op[row * 256] = acc[ms][r];
      }
    }
  }
}

extern "C" void kernel_launch(void* const* d_in, const int* in_sizes, int n_in,
                              void* d_out, int out_size, void* d_ws, size_t ws_size,
                              hipStream_t stream) {
  const float* i0 = (const float*)d_in[0];
  const float* i1 = (const float*)d_in[1];
  const float* W1 = (const float*)d_in[2];
  const float* W2 = (const float*)d_in[3];
  const float* a1 = (const float*)d_in[4];
  const float* a2 = (const float*)d_in[5];
  u16* Wb = (u16*)d_ws;   // 4 x 256x256 bf16 = 512 KB

  copy_convert<<<dim3(256, 2), 256, 0, stream>>>(a1, a2, Wb);
  transpose_convert<<<dim3(8, 8, 2), dim3(32, 8), 0, stream>>>(W1, W2, Wb + 2 * 65536);
  fused<<<NBLK, NT, 0, stream>>>(i0, i1, Wb, (float*)d_out);
}

// Round 2
// 257.611 us; speedup vs baseline: 1.3648x; 1.3648x over previous
//
#include <hip/hip_runtime.h>

#define D256 256
#define TOTROWS 65536   // B*A*I = 4*32*512
#define BM 64
#define LDW 264         // padded row stride in u16 (528 B = 33 x 16B chunks)
#define NBLK (TOTROWS / BM)   // 1024
#define NT 512                // 8 waves

typedef unsigned short u16;
typedef unsigned int u32;
typedef __attribute__((ext_vector_type(8))) short bf16x8;
typedef __attribute__((ext_vector_type(16))) float f32x16;

__device__ __forceinline__ float b2f(u16 u) {
  union { u32 i; float f; } v; v.i = ((u32)u) << 16; return v.f;
}
__device__ __forceinline__ u16 f2b(float f) {
  union { float f; u32 i; } v; v.f = f;
  return (u16)((v.i + 0x7fffu + ((v.i >> 16) & 1u)) >> 16);  // RNE
}
__device__ __forceinline__ u32 scale2(u32 u, float s) {
  float lo = b2f((u16)(u & 0xffffu)) * s;
  float hi = b2f((u16)(u >> 16)) * s;
  return (u32)f2b(lo) | ((u32)f2b(hi) << 16);
}

// attn1 -> Wb[0] (as-is, row-major [j][k]), attn2 -> Wb[1]
__global__ void copy_convert(const float* __restrict__ a1,
                             const float* __restrict__ a2,
                             u16* __restrict__ out) {
  const int m = blockIdx.y;
  const float* src = m ? a2 : a1;
  const int idx = blockIdx.x * 256 + threadIdx.x;
  out[m * 65536 + idx] = f2b(src[idx]);
}

// W1 -> Wb[2] transposed ([n][j] = W1[j][n]), W2 -> Wb[3]
__global__ void transpose_convert(const float* __restrict__ W1,
                                  const float* __restrict__ W2,
                                  u16* __restrict__ out) {
  __shared__ float tile[32][33];
  const int m = blockIdx.z;
  const float* src = m ? W2 : W1;
  const int bx = blockIdx.x, by = blockIdx.y;
  const int tx = threadIdx.x, ty = threadIdx.y;
#pragma unroll
  for (int i = ty; i < 32; i += 8)
    tile[i][tx] = src[(by * 32 + i) * 256 + bx * 32 + tx];
  __syncthreads();
#pragma unroll
  for (int i = ty; i < 32; i += 8)
    out[m * 65536 + (bx * 32 + i) * 256 + by * 32 + tx] = f2b(tile[tx][i]);
}

__global__ __launch_bounds__(NT, 4)
void fused(const float* __restrict__ X0g, const float* __restrict__ X1g,
           const u16* __restrict__ Wb, float* __restrict__ outg) {
  __shared__ u16 lX0[BM][LDW];   // 33.75 KB (padded: +8 u16/row kills bank conflicts)
  __shared__ u16 lX1[BM][LDW];   // 33.75 KB
  __shared__ float sp0[BM], sp1[BM], sc0[BM], sc1[BM];

  const int t = threadIdx.x;
  const int row0 = blockIdx.x * BM;

  if (t < BM) { sp0[t] = 0.f; sp1[t] = 0.f; }

  // ---- stage X tiles: fp32 global -> bf16 LDS (read inputs exactly once) ----
  {
    const float4* g0 = (const float4*)(X0g + (size_t)row0 * D256);
    const float4* g1 = (const float4*)(X1g + (size_t)row0 * D256);
    ushort4* s0 = (ushort4*)&lX0[0][0];   // row stride = 66 ushort4
    ushort4* s1 = (ushort4*)&lX1[0][0];
#pragma unroll
    for (int i = 0; i < 8; i++) {
      const int e = i * NT + t;         // 4096 float4 per tile; 64 per row
      const int row = e >> 6;
      const int col = e & 63;
      float4 a = g0[e];
      float4 b = g1[e];
      ushort4 pa, pb;
      pa.x = f2b(a.x); pa.y = f2b(a.y); pa.z = f2b(a.z); pa.w = f2b(a.w);
      pb.x = f2b(b.x); pb.y = f2b(b.y); pb.z = f2b(b.z); pb.w = f2b(b.w);
      s0[row * 66 + col] = pa;
      s1[row * 66 + col] = pb;
    }
  }
  __syncthreads();

  const int ln  = t & 63;
  const int wv  = t >> 6;    // wave 0..7, owns 32-col strip
  const int l31 = ln & 31;
  const int lh  = ln >> 5;
  const int cb  = wv * 32;

  // ---- gating: s0[r] = sum_j X1[r,j] * (X0 @ attn1^T)[r,j]; s1 symmetric ----
#pragma unroll
  for (int g = 0; g < 2; g++) {
    const u16* Wg = Wb + (g ? 65536 : 0);
    const u16(*Am)[LDW] = g ? lX1 : lX0;
    const u16(*Om)[LDW] = g ? lX0 : lX1;
    float* sp = g ? sp1 : sp0;

    f32x16 acc[2];
#pragma unroll
    for (int ms = 0; ms < 2; ms++)
#pragma unroll
      for (int i = 0; i < 16; i++) acc[ms][i] = 0.f;

    const u16* wrow = Wg + (cb + l31) * 256 + lh * 8;
#pragma unroll 4
    for (int k = 0; k < 16; k++) {            // K=256, 16 per MFMA
      bf16x8 bf = *(const bf16x8*)(wrow + k * 16);
#pragma unroll
      for (int ms = 0; ms < 2; ms++) {
        bf16x8 af = *(const bf16x8*)(&Am[ms * 32 + l31][k * 16 + lh * 8]);
        acc[ms] = __builtin_amdgcn_mfma_f32_32x32x16_bf16(af, bf, acc[ms], 0, 0, 0);
      }
    }

    // multiply by other operand, reduce over the 32 cols of this strip
#pragma unroll
    for (int ms = 0; ms < 2; ms++) {
#pragma unroll
      for (int r = 0; r < 16; r++) {
        const int row = ms * 32 + (r & 3) + 8 * (r >> 2) + 4 * lh;
        float v = acc[ms][r] * b2f(Om[row][cb + l31]);
        v += __shfl_xor(v, 1, 32);
        v += __shfl_xor(v, 2, 32);
        v += __shfl_xor(v, 4, 32);
        v += __shfl_xor(v, 8, 32);
        v += __shfl_xor(v, 16, 32);
        if (l31 == 0) atomicAdd(&sp[row], v);
      }
    }
  }
  __syncthreads();

  if (t < BM) {
    sc0[t] = 1.f + 1.f / (1.f + __expf(-sp0[t]));
    sc1[t] = 1.f + 1.f / (1.f + __expf(-sp1[t]));
  }
  __syncthreads();

  // ---- rescale rows in place: (1+g) * x, bf16 ----
  {
    uint2* p0 = (uint2*)&lX0[0][0];   // row stride = 66 uint2
    uint2* p1 = (uint2*)&lX1[0][0];
#pragma unroll
    for (int i = 0; i < 8; i++) {
      const int c = i * NT + t;     // 4096 uint2 chunks per tile; 64 per row
      const int row = c >> 6;       // wave-uniform -> broadcast scale read
      const int col = c & 63;
      const float s0v = sc0[row];
      const float s1v = sc1[row];
      uint2 a = p0[row * 66 + col];
      a.x = scale2(a.x, s0v); a.y = scale2(a.y, s0v);
      p0[row * 66 + col] = a;
      uint2 b = p1[row * 66 + col];
      b.x = scale2(b.x, s1v); b.y = scale2(b.y, s1v);
      p1[row * 66 + col] = b;
    }
  }
  __syncthreads();

  // ---- projection: out = r0 @ W1 + r1 @ W2 (concatenated K=512) ----
  {
    f32x16 acc[2];
#pragma unroll
    for (int ms = 0; ms < 2; ms++)
#pragma unroll
      for (int i = 0; i < 16; i++) acc[ms][i] = 0.f;

    const u16* w1r = Wb + 2 * 65536 + (cb + l31) * 256 + lh * 8;
    const u16* w2r = Wb + 3 * 65536 + (cb + l31) * 256 + lh * 8;
#pragma unroll 4
    for (int k = 0; k < 16; k++) {
      bf16x8 bf = *(const bf16x8*)(w1r + k * 16);
#pragma unroll
      for (int ms = 0; ms < 2; ms++) {
        bf16x8 af = *(const bf16x8*)(&lX0[ms * 32 + l31][k * 16 + lh * 8]);
        acc[ms] = __builtin_amdgcn_mfma_f32_32x32x16_bf16(af, bf, acc[ms], 0, 0, 0);
      }
    }
#pragma unroll 4
    for (int k = 0; k < 16; k++) {
      bf16x8 bf = *(const bf16x8*)(w2r + k * 16);
#pragma unroll
      for (int ms = 0; ms < 2; ms++) {
        bf16x8 af = *(const bf16x8*)(&lX1[ms * 32 + l31][k * 16 + lh * 8]);
        acc[ms] = __builtin_amdgcn_mfma_f32_32x32x16_bf16(af, bf, acc[ms], 0, 0, 0);
      }
    }

    float* op = outg + (size_t)row0 * 256 + cb + l31;
#pragma unroll
    for (int ms = 0; ms < 2; ms++) {
#pragma unroll
      for (int r = 0; r < 16; r++) {
        const int row = ms * 32 + (r & 3) + 8 * (r >> 2) + 4 * lh;
        op[row * 256] = acc[ms][r];
      }
    }
  }
}

extern "C" void kernel_launch(void* const* d_in, const int* in_sizes, int n_in,
                              void* d_out, int out_size, void* d_ws, size_t ws_size,
                              hipStream_t stream) {
  const float* i0 = (const float*)d_in[0];
  const float* i1 = (const float*)d_in[1];
  const float* W1 = (const float*)d_in[2];
  const float* W2 = (const float*)d_in[3];
  const float* a1 = (const float*)d_in[4];
  const float* a2 = (const float*)d_in[5];
  u16* Wb = (u16*)d_ws;   // 4 x 256x256 bf16 = 512 KB

  copy_convert<<<dim3(256, 2), 256, 0, stream>>>(a1, a2, Wb);
  transpose_convert<<<dim3(8, 8, 2), dim3(32, 8), 0, stream>>>(W1, W2, Wb + 2 * 65536);
  fused<<<NBLK, NT, 0, stream>>>(i0, i1, (float*)d_out ? (const u16*)Wb : (const u16*)Wb, (float*)d_out);
}